// Round 7
// baseline (812.607 us; speedup 1.0000x reference)
//
#include <hip/hip_runtime.h>
#include <hip/hip_bf16.h>

typedef __bf16 bf16;
typedef bf16 bf16x8 __attribute__((ext_vector_type(8)));
typedef bf16 bf16x4 __attribute__((ext_vector_type(4)));
typedef bf16 bf16x2 __attribute__((ext_vector_type(2)));
typedef float f32x4 __attribute__((ext_vector_type(4)));

#define MFMA16(a, b, c) __builtin_amdgcn_mfma_f32_16x16x32_bf16(a, b, c, 0, 0, 0)

constexpr int BB = 2, SS = 2048, DD = 4096, HH = 32, KVHH = 8, HDD = 128;
constexpr int QDIM = HH * HDD;     // 4096
constexpr int KVDIM = KVHH * HDD;  // 1024
constexpr int NQKV = QDIM + 2 * KVDIM;  // 6144
constexpr int LDX = NQKV;

__device__ inline void gload16(const bf16* g, bf16* l) {
    __builtin_amdgcn_global_load_lds((const __attribute__((address_space(1))) void*)g,
                                     (__attribute__((address_space(3))) void*)l, 16, 0, 0);
}

union U32BF2 { unsigned int u; bf16x2 v; };

// ---------------- fp32 -> bf16 convert (x) ----------------
__global__ __launch_bounds__(256) void cvt_bf16(const float* __restrict__ src,
                                                bf16* __restrict__ dst, int n4) {
    int i = blockIdx.x * 256 + threadIdx.x;
    if (i >= n4) return;
    float4 v = ((const float4*)src)[i];
    bf16x4 o;
    o[0] = (bf16)v.x; o[1] = (bf16)v.y; o[2] = (bf16)v.z; o[3] = (bf16)v.w;
    ((bf16x4*)dst)[i] = o;
}

// ---------------- weight transpose + fp32->bf16 ----------------
__global__ __launch_bounds__(256) void transpose_w(const float* __restrict__ src,
                                                   bf16* __restrict__ dst, int R, int C) {
    __shared__ bf16 t[32][33];
    int tx = threadIdx.x & 31, ty = threadIdx.x >> 5;
    int r0 = blockIdx.y * 32, c0 = blockIdx.x * 32;
#pragma unroll
    for (int i = 0; i < 4; i++)
        t[ty + i * 8][tx] = (bf16)src[(long)(r0 + ty + i * 8) * C + c0 + tx];
    __syncthreads();
#pragma unroll
    for (int i = 0; i < 4; i++)
        dst[(long)(c0 + ty + i * 8) * R + r0 + tx] = t[tx][ty + i * 8];
}

// ------------- V transpose from XQKV: Vt[((b*8+kvh)*128+hd)][pos] -------------
__global__ __launch_bounds__(256) void transpose_v(const bf16* __restrict__ XQKV,
                                                   bf16* __restrict__ Vt) {
    __shared__ bf16 t[32][33];
    int z = blockIdx.z, b = z >> 3, kvh = z & 7;
    int h0 = blockIdx.x * 32, p0 = blockIdx.y * 32;
    int tx = threadIdx.x & 31, ty = threadIdx.x >> 5;
#pragma unroll
    for (int i = 0; i < 4; i++)
        t[ty + i * 8][tx] = XQKV[(long)(b * SS + p0 + ty + i * 8) * LDX + QDIM + KVDIM +
                                 kvh * HDD + h0 + tx];
    __syncthreads();
#pragma unroll
    for (int i = 0; i < 4; i++)
        Vt[((long)(b * KVHH + kvh) * HDD + h0 + ty + i * 8) * SS + p0 + tx] =
            t[tx][ty + i * 8];
}

// ---- RoPE on Q section of XQKV, in place, uint-packed pairs ----
// NOTE: folds the attention scale 1/sqrt(128)*log2(e) into Q here, so QK^T
// scores come out of the MFMA pre-scaled (saves a v_mul per score in attn_k).
__global__ __launch_bounds__(256) void rope_q(bf16* __restrict__ X,
                                              const float* __restrict__ fc,
                                              const float* __restrict__ fs) {
    const float c2 = 0.08838834764831845f * 1.4426950408889634f;
    long t = (long)blockIdx.x * 256 + threadIdx.x;  // ((b*S+pos)*H + h)*64 + i2
    int i2 = (int)(t & 63);
    long u = t >> 6;
    int hh = (int)(u & 31);
    long bp = u >> 5;
    int pos = (int)(bp & (SS - 1));
    unsigned int* p = (unsigned int*)&X[bp * LDX + hh * HDD + 2 * i2];
    U32BF2 cv; cv.u = *p;
    float a = (float)cv.v[0], bb = (float)cv.v[1];
    float c = fc[pos * 64 + i2], s = fs[pos * 64 + i2];
    U32BF2 o;
    o.v[0] = (bf16)((a * c - bb * s) * c2);
    o.v[1] = (bf16)((a * s + bb * c) * c2);
    *p = o.u;
}

// ---- RoPE on K section of XQKV -> contiguous Kc[((b*8+kvh)*S+pos)*128+hd] ----
__global__ __launch_bounds__(256) void rope_kc(const bf16* __restrict__ X,
                                               const float* __restrict__ fc,
                                               const float* __restrict__ fs,
                                               bf16* __restrict__ Kc) {
    long t = (long)blockIdx.x * 256 + threadIdx.x;  // ((bk)*S+pos)*64 + i2
    int i2 = (int)(t & 63);
    long u = t >> 6;
    int pos = (int)(u & (SS - 1));
    int bk = (int)(u >> 11);
    int b = bk >> 3, kvh = bk & 7;
    const unsigned int* p =
        (const unsigned int*)&X[((long)(b * SS) + pos) * LDX + QDIM + kvh * HDD + 2 * i2];
    U32BF2 cv; cv.u = *p;
    float a = (float)cv.v[0], bb = (float)cv.v[1];
    float c = fc[pos * 64 + i2], s = fs[pos * 64 + i2];
    U32BF2 o;
    o.v[0] = (bf16)(a * c - bb * s);
    o.v[1] = (bf16)(a * s + bb * c);
    ((unsigned int*)Kc)[u * 64 + i2] = o.u;
}

// --------- suffix sums of V tiles from Vt: Suf[bk][t][hd] = sum_{j>=t*64} v_j ---------
__global__ __launch_bounds__(256) void sufv_k(const bf16* __restrict__ Vt,
                                              float* __restrict__ Suf) {
    __shared__ float ts[128][33];
    int bk = blockIdx.x;
    int hd = threadIdx.x & 127, tg = threadIdx.x >> 7;
    const bf16* row = Vt + ((long)bk * HDD + hd) * SS;
#pragma unroll
    for (int tt = 0; tt < 16; tt++) {
        int t = tg * 16 + tt;
        const bf16* p = row + t * 64;
        float s = 0.f;
#pragma unroll
        for (int j = 0; j < 8; j++) {
            bf16x8 v = *(const bf16x8*)&p[j * 8];
#pragma unroll
            for (int e = 0; e < 8; e++) s += (float)v[e];
        }
        ts[hd][t] = s;
    }
    __syncthreads();
    if (threadIdx.x < 128) {
        int h2 = threadIdx.x;
        float run = 0.f;
        Suf[((long)bk * 33 + 32) * HDD + h2] = 0.f;
        for (int t = 31; t >= 1; t--) {
            run += ts[h2][t];
            Suf[((long)bk * 33 + t) * HDD + h2] = run;
        }
    }
}

// ------- GEMM v4: 3-stage pipelined, BM=128 BN=256 BK=32, 8 waves (2Mx4N) -------
// r5 counters: bank-conflict 0 (T2 swizzle verified), FETCH 211MB (L3-resident).
// r6 change: UNPIN the schedule. The r5 lgkmcnt(0)+sched_barrier(0) serialized
//   8 ds_read_b128 (~96cy) before the 16-MFMA cluster (~80cy); plain vector loads
//   need no fence (rule #18 is for inline-asm reads) and the compiler emits exact
//   counted lgkmcnt, interleaving reads into MFMA. Reads issued in af/bf pairs so
//   the first MFMA depends on 2 reads, not 5. stage(t+2) moved to loop top so the
//   VMEM issue leads the compute phase. vmcnt(3) at tile end unchanged (T4: tile
//   t+2's 3 loads stay in flight across the barrier; never drains mid-loop).
template <typename CT>
__global__ __launch_bounds__(512, 4) void gemm3s(const bf16* __restrict__ A,
                                                 const bf16* __restrict__ BT,
                                                 CT* __restrict__ C, int M, int N, int K) {
    constexpr int BM = 128, BN = 256, BK = 32;
    constexpr int ASZ = BM * BK;       // 4096 elems (8 KB)
    constexpr int BSZ = BN * BK;       // 8192 elems (16 KB)
    constexpr int STG = ASZ + BSZ;     // 12288 elems per stage
    __shared__ bf16 LDS[3 * STG];      // 72 KB
    const int tid = threadIdx.x;
    const int lane = tid & 63, w = tid >> 6;
    const int quad = lane >> 4, lcol = lane & 15;
    const int m0 = blockIdx.y * BM, n0 = blockIdx.x * BN;
    const int wm = (w >> 2) * 64, wn = (w & 3) * 64;
    // staging: LDS slot j holds phys chunk (j&3) of row j>>2; phys = logical^((row>>1)&3)
    // so the global source reads logical chunk (j&3)^((j>>3)&3)  [involution]
    const int arow = tid >> 2, ac = (tid & 3) ^ ((tid >> 3) & 3);
    const int brow1 = (tid + 512) >> 2, bc1 = ((tid + 512) & 3) ^ (((tid + 512) >> 3) & 3);
    const bf16* gA = &A[(long)(m0 + arow) * K + ac * 8];
    const bf16* gB0 = &BT[(long)(n0 + arow) * K + ac * 8];
    const bf16* gB1 = &BT[(long)(n0 + brow1) * K + bc1 * 8];
    // fragment reads: logical chunk quad of row (wm|wn)+i*16+lcol -> phys quad^((lcol>>1)&3)
    const int xs = (quad ^ ((lcol >> 1) & 3)) * 8;
    const int aro = (wm + lcol) * BK + xs;
    const int bro = (wn + lcol) * BK + xs;
    const int NKT = K / BK;
    f32x4 acc[4][4] = {};

    auto stage = [&](int t) {
        const int bo = (t % 3) * STG;
        const long ko = (long)t * BK;
        gload16(gA + ko, &LDS[bo + tid * 8]);
        gload16(gB0 + ko, &LDS[bo + ASZ + tid * 8]);
        gload16(gB1 + ko, &LDS[bo + ASZ + (512 + tid) * 8]);
    };

    stage(0);
    stage(1);
    asm volatile("s_waitcnt vmcnt(3)" ::: "memory");  // tile 0 landed
    __builtin_amdgcn_s_barrier();

    for (int t = 0; t < NKT; ++t) {
        const int bo = (t % 3) * STG;
        if (t + 2 < NKT) stage(t + 2);  // VMEM issue leads the compute phase
        const bf16* la = &LDS[bo + aro];
        const bf16* lb = &LDS[bo + ASZ + bro];
        bf16x8 af[4], bfr[4];
#pragma unroll
        for (int i = 0; i < 4; i++) {   // paired so MFMA(0,0) depends on 2 reads
            af[i]  = *(const bf16x8*)&la[i * 16 * BK];
            bfr[i] = *(const bf16x8*)&lb[i * 16 * BK];
        }
        __builtin_amdgcn_s_setprio(1);
#pragma unroll
        for (int i = 0; i < 4; i++)
#pragma unroll
            for (int j = 0; j < 4; j++) acc[i][j] = MFMA16(af[i], bfr[j], acc[i][j]);
        __builtin_amdgcn_s_setprio(0);
        // retire tile t+1's loads; keep tile t+2's 3 loads in flight across the barrier
        if (t + 2 < NKT) asm volatile("s_waitcnt vmcnt(3)" ::: "memory");
        else             asm volatile("s_waitcnt vmcnt(0)" ::: "memory");
        __builtin_amdgcn_s_barrier();
    }
#pragma unroll
    for (int i = 0; i < 4; i++)
#pragma unroll
        for (int j = 0; j < 4; j++)
#pragma unroll
            for (int r = 0; r < 4; r++) {
                int row = m0 + wm + i * 16 + quad * 4 + r;
                int col = n0 + wn + j * 16 + lcol;
                C[(long)row * N + col] = (CT)acc[i][j][r];
            }
}

// -------- attention v5: 8 waves x 16 q-rows, swapped QK^T, in-register softmax --------
__global__ __launch_bounds__(512, 4) void attn_k(const bf16* __restrict__ XQKV,
                                                 const bf16* __restrict__ Kc,
                                                 const bf16* __restrict__ Vt,
                                                 const float* __restrict__ Suf,
                                                 bf16* __restrict__ AO) {
    __shared__ bf16 Ks[2][64 * 128];    // 16B-slot swizzled, double-buffered
    __shared__ bf16 Vs[2][128 * 64];    // 16B-slot swizzled, double-buffered
    __shared__ bf16 Pl[8][16 * 64];     // per-wave P roundtrip, XOR-swizzled rows
    const int tid = threadIdx.x;
    const int lane = tid & 63, w = tid >> 6;       // w in 0..7
    const int quad = lane >> 4, lcol = lane & 15;
    const int h = blockIdx.y, b = blockIdx.z;
    const int kvh = h >> 2;

    const bf16* KcB = Kc + (long)((b * KVHH + kvh) * SS) * HDD;
    const bf16* VtB = Vt + (long)((b * KVHH + kvh) * HDD) * SS;

    int kofs[2], vofs[2];
#pragma unroll
    for (int i = 0; i < 2; i++) {
        int j = i * 512 + tid;
        int p = j >> 4, cp = j & 15, c = cp ^ (p & 7);
        kofs[i] = p * HDD + c * 8;
        int r = j >> 3, cp2 = j & 7, cv = cp2 ^ (r & 7);
        vofs[i] = r * SS + cv * 8;
    }

    auto stageKV = [&](int buf, int kb0s) {
        bf16* ksb = &Ks[buf][0];
        bf16* vsb = &Vs[buf][0];
#pragma unroll
        for (int i = 0; i < 2; i++)
            gload16(KcB + (long)kb0s * HDD + kofs[i], &ksb[(i * 512 + tid) * 8]);
#pragma unroll
        for (int i = 0; i < 2; i++)
            gload16(VtB + (long)kb0s + vofs[i], &vsb[(i * 512 + tid) * 8]);
    };

    for (int rep = 0; rep < 2; rep++) {
        const int qc = rep == 0 ? 15 - (int)blockIdx.x : (int)blockIdx.x;
        const int qbase = qc * 128 + w * 16;
        const int NT = 2 * qc + 2;
        const int qpos = qbase + lcol;

        bf16x8 qf[4];
#pragma unroll
        for (int kc = 0; kc < 4; kc++)
            qf[kc] = *(const bf16x8*)&XQKV[((long)(b * SS) + qbase + lcol) * LDX +
                                           h * HDD + kc * 32 + quad * 8];
        f32x4 oacc[8] = {};
        float m2 = -1e30f, l = 0.f;

        stageKV(0, 0);
        asm volatile("s_waitcnt vmcnt(0)" ::: "memory");
        __builtin_amdgcn_s_barrier();

        int cur = 0;
        for (int kt = 0; kt < NT; kt++) {
            const int kb0 = kt * 64;
            stageKV(cur ^ 1, (kt + 1 < NT ? kt + 1 : kt) * 64);

            const bf16* KsC = &Ks[cur][0];
            const bf16* VsC = &Vs[cur][0];
            f32x4 sa[4] = {};
            __builtin_amdgcn_s_setprio(1);
#pragma unroll
            for (int ch = 0; ch < 4; ch++) {
                int p = ch * 16 + lcol;
#pragma unroll
                for (int kc = 0; kc < 4; kc++) {
                    int c = kc * 4 + quad;
                    bf16x8 kf = *(const bf16x8*)&KsC[(p * 16 + (c ^ (p & 7))) * 8];
                    sa[ch] = MFMA16(kf, qf[kc], sa[ch]);
                }
            }
            __builtin_amdgcn_s_setprio(0);
            if (kb0 + 63 > qbase) {
#pragma unroll
                for (int ch = 0; ch < 4; ch++)
#pragma unroll
                    for (int r = 0; r < 4; r++)
                        if (kb0 + ch * 16 + quad * 4 + r > qpos) sa[ch][r] = 0.f;
            }
            f32x4 mx = sa[0];
#pragma unroll
            for (int ch = 1; ch < 4; ch++)
#pragma unroll
                for (int r = 0; r < 4; r++) mx[r] = fmaxf(mx[r], sa[ch][r]);
            float mt = fmaxf(fmaxf(mx[0], mx[1]), fmaxf(mx[2], mx[3]));
            mt = fmaxf(mt, __shfl_xor(mt, 16, 64));
            mt = fmaxf(mt, __shfl_xor(mt, 32, 64));
            float mnew = fmaxf(m2, mt);
            float alpha = exp2f(m2 - mnew);
            m2 = mnew;
            float rs = 0.f;
            const int xm = (lcol & 7) << 3;
            bf16* plw = &Pl[w][0];
#pragma unroll
            for (int ch = 0; ch < 4; ch++) {
                bf16x4 pv;
#pragma unroll
                for (int r = 0; r < 4; r++) {
                    float e = exp2f(sa[ch][r] - mnew);
                    rs += e;
                    pv[r] = (bf16)e;
                }
                *(bf16x4*)&plw[lcol * 64 + ((ch * 16 + quad * 4) ^ xm)] = pv;
            }
            l = l * alpha + rs;
            bf16x8 pf0 = *(const bf16x8*)&plw[lcol * 64 + ((quad * 8) ^ xm)];
            bf16x8 pf1 = *(const bf16x8*)&plw[lcol * 64 + ((32 + quad * 8) ^ xm)];
            float a4[4];
#pragma unroll
            for (int r = 0; r < 4; r++)
                a4[r] = __shfl(alpha, (quad << 4) | (quad * 4 + r), 64);
            __builtin_amdgcn_s_setprio(1);
#pragma unroll
            for (int nj = 0; nj < 8; nj++) {
                int rr = nj * 16 + lcol;
                bf16x8 vf0 = *(const bf16x8*)&VsC[(rr * 8 + (quad ^ (rr & 7))) * 8];
                bf16x8 vf1 = *(const bf16x8*)&VsC[(rr * 8 + ((4 + quad) ^ (rr & 7))) * 8];
                f32x4 o = oacc[nj];
#pragma unroll
                for (int r = 0; r < 4; r++) o[r] *= a4[r];
                o = MFMA16(pf0, vf0, o);
                o = MFMA16(pf1, vf1, o);
                oacc[nj] = o;
            }
            __builtin_amdgcn_s_setprio(0);
            asm volatile("s_waitcnt vmcnt(0)" ::: "memory");
            __builtin_amdgcn_s_barrier();
            cur ^= 1;
        }
        l += __shfl_xor(l, 16, 64);
        l += __shfl_xor(l, 32, 64);
        const int cnt = SS - NT * 64;
        float mf = (cnt > 0) ? fmaxf(m2, 0.f) : m2;
        float so = exp2f(m2 - mf);
        float sm = exp2f(-mf);
        float rz = 1.f / (l * so + (float)cnt * sm);
        float so4[4], sm4[4], rz4[4];
#pragma unroll
        for (int r = 0; r < 4; r++) {
            int src = (quad << 4) | (quad * 4 + r);
            so4[r] = __shfl(so, src, 64);
            sm4[r] = __shfl(sm, src, 64);
            rz4[r] = __shfl(rz, src, 64);
        }
        const float* sufp = &Suf[((long)((b * KVHH + kvh) * 33) + NT) * HDD];
#pragma unroll
        for (int nj = 0; nj < 8; nj++) {
            float suf = sufp[nj * 16 + lcol];
#pragma unroll
            for (int r = 0; r < 4; r++) {
                float o = (oacc[nj][r] * so4[r] + sm4[r] * suf) * rz4[r];
                AO[((long)(b * SS) + qbase + quad * 4 + r) * QDIM + h * HDD +
                   nj * 16 + lcol] = (bf16)o;
            }
        }
    }
}

extern "C" void kernel_launch(void* const* d_in, const int* in_sizes, int n_in,
                              void* d_out, int out_size, void* d_ws, size_t ws_size,
                              hipStream_t stream) {
    const float* x  = (const float*)d_in[0];
    const float* fc = (const float*)d_in[1];
    const float* fs = (const float*)d_in[2];
    const float* wq = (const float*)d_in[4];
    const float* wk = (const float*)d_in[5];
    const float* wv = (const float*)d_in[6];
    const float* wo = (const float*)d_in[7];
    float* out = (float*)d_out;

    char* ws = (char*)d_ws;
    bf16* Wt   = (bf16*)ws; ws += (long)NQKV * DD * 2;             // 50.3 MB
    bf16* woT  = (bf16*)ws; ws += (long)DD * QDIM * 2;             // 33.6 MB
    bf16* XQKV = (bf16*)ws; ws += (long)BB * SS * NQKV * 2;        // 50.3 MB
    bf16* Vt   = (bf16*)ws; ws += (long)BB * KVHH * HDD * SS * 2;  // 8.4 MB
    bf16* Xb   = (bf16*)ws; ws += (long)BB * SS * DD * 2;          // 33.6 MB
    float* Suf = (float*)ws; ws += (long)BB * KVHH * 33 * HDD * 4; // 270 KB
    bf16* AO = Xb;            // Xb dead after QKV gemm
    bf16* Kc = Wt;            // Wt dead after QKV gemm (8.4 MB needed)

    const int M = BB * SS;  // 4096

    cvt_bf16<<<(DD * M / 4 + 255) / 256, 256, 0, stream>>>(x, Xb, DD * M / 4);

    transpose_w<<<dim3(QDIM / 32, DD / 32), 256, 0, stream>>>(wq, Wt, DD, QDIM);
    transpose_w<<<dim3(KVDIM / 32, DD / 32), 256, 0, stream>>>(wk, Wt + (long)QDIM * DD, DD, KVDIM);
    transpose_w<<<dim3(KVDIM / 32, DD / 32), 256, 0, stream>>>(wv, Wt + (long)(QDIM + KVDIM) * DD, DD, KVDIM);
    transpose_w<<<dim3(DD / 32, QDIM / 32), 256, 0, stream>>>(wo, woT, QDIM, DD);

    gemm3s<bf16><<<dim3(NQKV / 256, M / 128), 512, 0, stream>>>(Xb, Wt, XQKV, M, NQKV, DD);

    rope_q<<<(int)(((long)BB * SS * HH * 64) / 256), 256, 0, stream>>>(XQKV, fc, fs);
    rope_kc<<<(int)(((long)BB * KVHH * SS * 64) / 256), 256, 0, stream>>>(XQKV, fc, fs, Kc);

    transpose_v<<<dim3(HDD / 32, SS / 32, BB * KVHH), 256, 0, stream>>>(XQKV, Vt);
    sufv_k<<<BB * KVHH, 256, 0, stream>>>(Vt, Suf);

    attn_k<<<dim3(8, HH, BB), 512, 0, stream>>>(XQKV, Kc, Vt, Suf, AO);

    gemm3s<float><<<dim3(DD / 256, M / 128), 512, 0, stream>>>(AO, woT, out, M, DD, QDIM);
}